// Round 1
// baseline (102.600 us; speedup 1.0000x reference)
//
#include <hip/hip_runtime.h>
#include <math.h>

#define PI_F 3.14159265358979323846f

struct c32 { float x, y; };

__device__ __forceinline__ c32 cmul(c32 a, c32 b){ return { a.x*b.x - a.y*b.y, a.x*b.y + a.y*b.x }; }
__device__ __forceinline__ c32 cadd(c32 a, c32 b){ return { a.x+b.x, a.y+b.y }; }

// 4-qubit state: shape (2,2,2,2), wire w = bit (3-w) of flat index.
// Apply general 2x2 complex [[A,B],[C,D]] on wire w.
__device__ __forceinline__ void apply_1q(c32 s[16], const int w, c32 A, c32 B, c32 C, c32 D){
  const int m = 8 >> w;
  #pragma unroll
  for (int i = 0; i < 16; i++){
    if (i & m) continue;
    c32 a = s[i], b = s[i | m];
    s[i]     = cadd(cmul(A,a), cmul(B,b));
    s[i | m] = cadd(cmul(C,a), cmul(D,b));
  }
}

// RX(t): [[c,-i s],[-i s, c]]
__device__ __forceinline__ void apply_rx(c32 s[16], const int w, float c, float sn){
  const int m = 8 >> w;
  #pragma unroll
  for (int i = 0; i < 16; i++){
    if (i & m) continue;
    c32 a = s[i], b = s[i | m];
    s[i]     = { c*a.x + sn*b.y, c*a.y - sn*b.x };
    s[i | m] = { c*b.x + sn*a.y, c*b.y - sn*a.x };
  }
}

// CRX: control wa, target wb; acts as RX on control=1 subspace
__device__ __forceinline__ void apply_crx(c32 s[16], const int wa, const int wb, float c, float sn){
  const int ma = 8 >> wa, mb = 8 >> wb;
  #pragma unroll
  for (int i = 0; i < 16; i++){
    if (!(i & ma) || (i & mb)) continue;
    c32 a = s[i], b = s[i | mb];
    s[i]      = { c*a.x + sn*b.y, c*a.y - sn*b.x };
    s[i | mb] = { c*b.x + sn*a.y, c*b.y - sn*a.x };
  }
}

__device__ __forceinline__ void apply_cnot(c32 s[16], const int wa, const int wb){
  const int ma = 8 >> wa, mb = 8 >> wb;
  #pragma unroll
  for (int i = 0; i < 16; i++){
    if (!(i & ma) || (i & mb)) continue;
    c32 t = s[i]; s[i] = s[i | mb]; s[i | mb] = t;
  }
}

// RZ(t) = diag(e^{-it/2}, e^{+it/2}); c=cos(t/2), sn=sin(t/2)
__device__ __forceinline__ void apply_rz(c32 s[16], const int w, float c, float sn){
  const int m = 8 >> w;
  #pragma unroll
  for (int i = 0; i < 16; i++){
    c32 a = s[i];
    float sg = (i & m) ? sn : -sn;
    s[i] = { c*a.x - sg*a.y, c*a.y + sg*a.x };
  }
}

// initQKV_on_wires: per pair (a,b): Rot(phi,th,om) on a; CRX on (a,b); CNOT on (a,b).
// Trig computed inline from the (wave-uniform) global params -> scalar-load path.
__device__ __forceinline__ void init_qkv(c32 s[16],
                                         const float* __restrict__ rotp,
                                         const float* __restrict__ crxp){
  constexpr int pa[8] = {0,1,2,3,0,1,2,3};
  constexpr int pb[8] = {1,2,3,0,3,0,1,2};
  #pragma unroll
  for (int g = 0; g < 8; g++){
    float phi = rotp[3*g], th = rotp[3*g+1], om = rotp[3*g+2];
    float c, sn, ca, sa, cb, sb;
    __sincosf(0.5f*th,       &sn, &c);
    __sincosf(0.5f*(phi+om), &sa, &ca);
    __sincosf(0.5f*(phi-om), &sb, &cb);
    // Rot = [[e^{-i a} c, -e^{i b} s],[e^{-i b} s, e^{i a} c]], a=(phi+om)/2, b=(phi-om)/2
    c32 A{  c*ca, -c*sa }, Bm{ -sn*cb, -sn*sb }, C{ sn*cb, -sn*sb }, D{ c*ca, c*sa };
    apply_1q(s, pa[g], A, Bm, C, D);
    float cc, cs; __sincosf(0.5f*crxp[g], &cs, &cc);
    apply_crx(s, pa[g], pb[g], cc, cs);
    apply_cnot(s, pa[g], pb[g]);
  }
}

__device__ __forceinline__ float expZ(const c32 s[16], const int w){
  const int m = 8 >> w;
  float r = 0.f;
  #pragma unroll
  for (int i = 0; i < 16; i++){
    float p = s[i].x*s[i].x + s[i].y*s[i].y;
    r += (i & m) ? -p : p;
  }
  return r;
}

__device__ __forceinline__ float expX(const c32 s[16], const int w){
  const int m = 8 >> w;
  float r = 0.f;
  #pragma unroll
  for (int i = 0; i < 16; i++){
    if (i & m) continue;
    r += s[i].x*s[(i|m)].x + s[i].y*s[(i|m)].y;
  }
  return 2.f*r;
}

#define LDS_STRIDE 97   // 97 % 32 == 1 -> 2-way bank aliasing on row reads (free)

__global__ __launch_bounds__(64, 1) void qc_main(
    const float* __restrict__ x1,
    const float* __restrict__ pre_w, const float* __restrict__ pre_b,
    const float* __restrict__ q_rot, const float* __restrict__ k_rot, const float* __restrict__ v_rot,
    const float* __restrict__ q_crx, const float* __restrict__ k_crx, const float* __restrict__ v_crx,
    const float* __restrict__ ln_w, const float* __restrict__ ln_b,
    const float* __restrict__ head_w, const float* __restrict__ head_b,
    float* __restrict__ out, int B){

  __shared__ float xs[64 * LDS_STRIDE];
  const int t = threadIdx.x;
  const int base = blockIdx.x * 64;

  // ---- stage this block's 64 x 96 slice of x1 into LDS (coalesced float4) ----
  {
    int rem = B - base; if (rem > 64) rem = 64;
    const int nf4 = rem * 24;                      // float4s in tile
    const float4* src = (const float4*)(x1 + (long)base * 96);
    #pragma unroll
    for (int k = 0; k < 24; k++){
      int g = t + 64*k;
      if (g < nf4){
        float4 v = src[g];
        int f = 4*g;
        int r = f / 96, cidx = f - 96*r;
        float* d = &xs[r*LDS_STRIDE + cidx];
        d[0]=v.x; d[1]=v.y; d[2]=v.z; d[3]=v.w;
      }
    }
  }
  __syncthreads();

  // ---- x = x1_row @ pre_w.T + pre_b  (pre_w reads are uniform -> scalar path) ----
  float xw[4];
  {
    float a0 = pre_b[0], a1 = pre_b[1], a2 = pre_b[2], a3 = pre_b[3];
    const float* row = &xs[t * LDS_STRIDE];
    #pragma unroll
    for (int j = 0; j < 96; j++){
      float v = row[j];
      a0 += v * pre_w[j];
      a1 += v * pre_w[96  + j];
      a2 += v * pre_w[192 + j];
      a3 += v * pre_w[288 + j];
    }
    xw[0]=a0; xw[1]=a1; xw[2]=a2; xw[3]=a3;
  }

  float cw[4], sw[4];
  #pragma unroll
  for (int w = 0; w < 4; w++) __sincosf(0.5f*xw[w], &sw[w], &cw[w]);

  // ---- k-circuit constant: cXk[w] = expX(U_k |0000>, w)  (batch-uniform; recomputed
  //      per thread — with 1 wave/block a masked single-thread version costs the same) ----
  float cxk[4];
  {
    c32 ks[16];
    #pragma unroll
    for (int i = 0; i < 16; i++) ks[i] = {0.f, 0.f};
    ks[0] = {1.f, 0.f};
    init_qkv(ks, k_rot, k_crx);
    #pragma unroll
    for (int w = 0; w < 4; w++) cxk[w] = expX(ks, w);
  }

  // ---- psi_RX = RX(x)|0000>, reused by q- and v-circuits ----
  c32 rx16[16];
  #pragma unroll
  for (int i = 0; i < 16; i++) rx16[i] = {0.f, 0.f};
  rx16[0] = {1.f, 0.f};
  #pragma unroll
  for (int w = 0; w < 4; w++) apply_rx(rx16, w, cw[w], sw[w]);

  // ---- q-circuit: psi_a = RX(x) U_q RX(x) |0>; score from expZ / expX*cXk ----
  float thc[4], ths[4];
  {
    c32 st[16];
    #pragma unroll
    for (int i = 0; i < 16; i++) st[i] = rx16[i];
    init_qkv(st, q_rot, q_crx);
    #pragma unroll
    for (int w = 0; w < 4; w++) apply_rx(st, w, cw[w], sw[w]);
    #pragma unroll
    for (int w = 0; w < 4; w++){
      float z  = expZ(st, w);
      float xm = expX(st, w) * cxk[w];
      float score = sqrtf(z*z + xm*xm);
      float th = tanhf(score) * PI_F;
      __sincosf(0.5f*th, &ths[w], &thc[w]);
    }
  }

  // ---- value circuit ----
  float o[8];
  {
    c32 st[16];
    #pragma unroll
    for (int i = 0; i < 16; i++) st[i] = rx16[i];
    init_qkv(st, v_rot, v_crx);
    #pragma unroll
    for (int w = 0; w < 4; w++) apply_rz(st, w, thc[w], ths[w]);
    apply_cnot(st, 0, 1);
    apply_cnot(st, 1, 2);
    apply_cnot(st, 2, 3);
    #pragma unroll
    for (int w = 0; w < 4; w++){ o[w] = expZ(st, w); o[4+w] = expX(st, w); }
  }

  // ---- LayerNorm(8) -> exact GELU -> head (8 -> 2) ----
  float mu = 0.f;
  #pragma unroll
  for (int j = 0; j < 8; j++) mu += o[j];
  mu *= 0.125f;
  float var = 0.f;
  #pragma unroll
  for (int j = 0; j < 8; j++){ float d = o[j] - mu; var += d*d; }
  var *= 0.125f;
  float inv = rsqrtf(var + 1e-5f);
  float h0 = head_b[0], h1 = head_b[1];
  #pragma unroll
  for (int j = 0; j < 8; j++){
    float y = (o[j] - mu) * inv * ln_w[j] + ln_b[j];
    float g = 0.5f * y * (1.f + erff(y * 0.70710678118f));
    h0 += g * head_w[j];
    h1 += g * head_w[8 + j];
  }

  const int sid = base + t;
  if (sid < B){
    float2 r2; r2.x = h0; r2.y = h1;
    ((float2*)out)[sid] = r2;
  }
}

extern "C" void kernel_launch(void* const* d_in, const int* in_sizes, int n_in,
                              void* d_out, int out_size, void* d_ws, size_t ws_size,
                              hipStream_t stream) {
  const float* x1     = (const float*)d_in[0];
  const float* pre_w  = (const float*)d_in[1];
  const float* pre_b  = (const float*)d_in[2];
  const float* q_rot  = (const float*)d_in[3];
  const float* k_rot  = (const float*)d_in[4];
  const float* v_rot  = (const float*)d_in[5];
  const float* q_crx  = (const float*)d_in[6];
  const float* k_crx  = (const float*)d_in[7];
  const float* v_crx  = (const float*)d_in[8];
  const float* ln_w   = (const float*)d_in[9];
  const float* ln_b   = (const float*)d_in[10];
  const float* head_w = (const float*)d_in[11];
  const float* head_b = (const float*)d_in[12];
  float* out = (float*)d_out;
  (void)d_ws; (void)ws_size; (void)n_in; (void)out_size;

  const int B = in_sizes[0] / 96;
  const int nb = (B + 63) / 64;
  qc_main<<<nb, 64, 0, stream>>>(x1, pre_w, pre_b,
                                 q_rot, k_rot, v_rot,
                                 q_crx, k_crx, v_crx,
                                 ln_w, ln_b, head_w, head_b,
                                 out, B);
}